// Round 1
// baseline (329.299 us; speedup 1.0000x reference)
//
#include <hip/hip_runtime.h>

#define NN 50000
#define NE 400000
#define NG 64

// ---------------------------------------------------------------------------
// Linear-GCN collapse:
//   x3 = A^3 X (W1W2W3) + (A^2 1)(b1^T W2 W3) + (A 1)(b2^T W3) + 1 b3^T
// where A = D^-1/2 (Adj + I) D^-1/2.
// Propagate Y=[X|1] (N x 4) through A three times; pool 6 scalars per node.
// ---------------------------------------------------------------------------

static __device__ __forceinline__ float wsum(float v) {
#pragma unroll
  for (int o = 32; o > 0; o >>= 1) v += __shfl_xor(v, o, 64);
  return v;
}

// deg = 1 (self loop), Y0 = [x0 x1 x2 1]
__global__ void k_init(const float* __restrict__ x, float* __restrict__ deg,
                       float* __restrict__ y0) {
  int n = blockIdx.x * blockDim.x + threadIdx.x;
  if (n < NN) {
    deg[n] = 1.0f;
    float4 v;
    v.x = x[3 * n + 0];
    v.y = x[3 * n + 1];
    v.z = x[3 * n + 2];
    v.w = 1.0f;
    reinterpret_cast<float4*>(y0)[n] = v;
  }
}

__global__ void k_deg(const int* __restrict__ dst, float* __restrict__ deg) {
  int e = blockIdx.x * blockDim.x + threadIdx.x;
  if (e < NE) atomicAdd(&deg[dst[e]], 1.0f);
}

// deg -> deg^{-1/2} in place
__global__ void k_fin_dis(float* __restrict__ deg) {
  int n = blockIdx.x * blockDim.x + threadIdx.x;
  if (n < NN) deg[n] = rsqrtf(deg[n]);
}

// out[n] = in[n] * dis[n]^2  (self-loop term; also serves as dest init)
__global__ void k_self(const float* __restrict__ dis, const float* __restrict__ in,
                       float* __restrict__ out) {
  int n = blockIdx.x * blockDim.x + threadIdx.x;
  if (n < NN) {
    float w = dis[n];
    w *= w;
    float4 v = reinterpret_cast<const float4*>(in)[n];
    v.x *= w; v.y *= w; v.z *= w; v.w *= w;
    reinterpret_cast<float4*>(out)[n] = v;
  }
}

// out[d] += in[s] * dis[s]*dis[d] for every edge
__global__ void k_edge(const int* __restrict__ src, const int* __restrict__ dst,
                       const float* __restrict__ dis, const float* __restrict__ in,
                       float* __restrict__ out) {
  int e = blockIdx.x * blockDim.x + threadIdx.x;
  if (e < NE) {
    int s = src[e], d = dst[e];
    float w = dis[s] * dis[d];
    float4 v = reinterpret_cast<const float4*>(in)[s];
    float* o = out + 4 * d;
    atomicAdd(o + 0, v.x * w);
    atomicAdd(o + 1, v.y * w);
    atomicAdd(o + 2, v.z * w);
    atomicAdd(o + 3, v.w * w);
  }
}

// one block, 192 threads: W123 = W1@W2@W3 (3x192), bW23 = b1@W2@W3,
// bW3 = b2@W3; also zero pooled bins.
__global__ void k_weights(const float* __restrict__ W1, const float* __restrict__ b1,
                          const float* __restrict__ W2, const float* __restrict__ b2,
                          const float* __restrict__ W3, float* __restrict__ W123,
                          float* __restrict__ bW23, float* __restrict__ bW3,
                          float* __restrict__ pooled) {
  __shared__ float w12[3 * 48];
  __shared__ float t48[48];
  int t = threadIdx.x;  // 192
  for (int i = t; i < NG * 8; i += 192) pooled[i] = 0.0f;
  if (t < 144) {
    int i = t / 48, k = t % 48;
    float a = 0.f;
    for (int j = 0; j < 24; ++j) a += W1[i * 24 + j] * W2[j * 48 + k];
    w12[t] = a;
  }
  if (t < 48) {
    float a = 0.f;
    for (int j = 0; j < 24; ++j) a += b1[j] * W2[j * 48 + t];
    t48[t] = a;
  }
  __syncthreads();
  float a0 = 0, a1 = 0, a2 = 0, ab = 0, ab3 = 0;
  for (int k = 0; k < 48; ++k) {
    float w3 = W3[k * 192 + t];
    a0 += w12[0 * 48 + k] * w3;
    a1 += w12[1 * 48 + k] * w3;
    a2 += w12[2 * 48 + k] * w3;
    ab += t48[k] * w3;
    ab3 += b2[k] * w3;
  }
  W123[t] = a0;
  W123[192 + t] = a1;
  W123[384 + t] = a2;
  bW23[t] = ab;
  bW3[t] = ab3;
}

// per-graph sums of (A^3 X)[:,0..2], (A^2 1), (A 1), count
__global__ void k_pool(const int* __restrict__ batch, const float* __restrict__ y1,
                       const float* __restrict__ y2, const float* __restrict__ y3,
                       float* __restrict__ pooled) {
  int n = blockIdx.x * blockDim.x + threadIdx.x;
  bool act = n < NN;
  int g = -1;
  float vx = 0, vy = 0, vz = 0, v1 = 0, v2 = 0, c = 0;
  if (act) {
    g = batch[n];
    float4 a = reinterpret_cast<const float4*>(y3)[n];
    vx = a.x; vy = a.y; vz = a.z;
    v1 = y2[4 * n + 3];  // A^2 1
    v2 = y1[4 * n + 3];  // A 1
    c = 1.0f;
  }
  int g0 = __shfl(g, 0, 64);
  bool uni = __all(g == g0);
  if (uni) {
    float sx = wsum(vx), sy = wsum(vy), sz = wsum(vz);
    float s1 = wsum(v1), s2 = wsum(v2), sc = wsum(c);
    if ((threadIdx.x & 63) == 0 && g0 >= 0) {
      float* p = pooled + 8 * g0;
      atomicAdd(p + 0, sx); atomicAdd(p + 1, sy); atomicAdd(p + 2, sz);
      atomicAdd(p + 3, s1); atomicAdd(p + 4, s2); atomicAdd(p + 5, sc);
    }
  } else if (act) {
    float* p = pooled + 8 * g;
    atomicAdd(p + 0, vx); atomicAdd(p + 1, vy); atomicAdd(p + 2, vz);
    atomicAdd(p + 3, v1); atomicAdd(p + 4, v2); atomicAdd(p + 5, c);
  }
}

__global__ void k_final(const float* __restrict__ pooled, const float* __restrict__ W123,
                        const float* __restrict__ bW23, const float* __restrict__ bW3,
                        const float* __restrict__ b3, float* __restrict__ out) {
  int g = blockIdx.x;   // 64
  int l = threadIdx.x;  // 192
  const float* p = pooled + 8 * g;
  float ic = 1.0f / fmaxf(p[5], 1.0f);
  float sx = p[0] * ic, sy = p[1] * ic, sz = p[2] * ic;
  float v1 = p[3] * ic, v2 = p[4] * ic;
  out[g * 192 + l] = sx * W123[l] + sy * W123[192 + l] + sz * W123[384 + l] +
                     v1 * bW23[l] + v2 * bW3[l] + b3[l];
}

extern "C" void kernel_launch(void* const* d_in, const int* in_sizes, int n_in,
                              void* d_out, int out_size, void* d_ws, size_t ws_size,
                              hipStream_t stream) {
  const float* x = (const float*)d_in[0];        // [NN,3]
  const int* edges = (const int*)d_in[1];        // [2,NE]
  const int* batch = (const int*)d_in[2];        // [NN]
  const float* W1 = (const float*)d_in[3];
  const float* b1 = (const float*)d_in[4];
  const float* W2 = (const float*)d_in[5];
  const float* b2 = (const float*)d_in[6];
  const float* W3 = (const float*)d_in[7];
  const float* b3 = (const float*)d_in[8];
  float* out = (float*)d_out;

  const int* src = edges;
  const int* dst = edges + NE;

  float* ws = (float*)d_ws;
  float* dis = ws;                 // NN  (deg, then deg^-1/2)
  float* y0 = ws + 50000;          // NN*4
  float* y1 = ws + 250000;         // NN*4
  float* y2 = ws + 450000;         // NN*4
  float* y3 = ws + 650000;         // NN*4
  float* pooled = ws + 850000;     // NG*8
  float* W123 = ws + 850512;       // 3*192
  float* bW23 = ws + 851088;       // 192
  float* bW3 = ws + 851280;        // 192

  dim3 bn((NN + 255) / 256), be((NE + 255) / 256), b256(256);

  k_init<<<bn, b256, 0, stream>>>(x, dis, y0);
  k_deg<<<be, b256, 0, stream>>>(dst, dis);
  k_fin_dis<<<bn, b256, 0, stream>>>(dis);

  k_self<<<bn, b256, 0, stream>>>(dis, y0, y1);
  k_edge<<<be, b256, 0, stream>>>(src, dst, dis, y0, y1);
  k_self<<<bn, b256, 0, stream>>>(dis, y1, y2);
  k_edge<<<be, b256, 0, stream>>>(src, dst, dis, y1, y2);
  k_self<<<bn, b256, 0, stream>>>(dis, y2, y3);
  k_edge<<<be, b256, 0, stream>>>(src, dst, dis, y2, y3);

  k_weights<<<1, 192, 0, stream>>>(W1, b1, W2, b2, W3, W123, bW23, bW3, pooled);
  k_pool<<<bn, b256, 0, stream>>>(batch, y1, y2, y3, pooled);
  k_final<<<NG, 192, 0, stream>>>(pooled, W123, bW23, bW3, b3, out);
}